// Round 2
// 953.850 us; speedup vs baseline: 1.0412x; 1.0412x over previous
//
#include <hip/hip_runtime.h>
#include <cstdint>

typedef _Float16 f16;
typedef _Float16 f16x8 __attribute__((ext_vector_type(8)));
typedef float    f32x4 __attribute__((ext_vector_type(4)));

// Problem: R=256, C=256, B=1, E=768, H=12, Dh=64. scaling = (1/8)/16 = 1/128.
// Tokens m = r*256 + i (x is (R,C,B,E) row-major).
//
// ws layout (bytes):
#define OFF_XH   0UL           // Xh 100 MB; DEAD after V-proj -> reused as Spart (50 MB) then CTXh (100 MB)
#define OFF_QT   100663296UL   // Qt  [h][i][r*64+d] f16, 100 MB
#define OFF_KT   201326592UL   // Kt  same layout
#define OFF_VT   301989888UL   // Vt2 [h][r][d][j]   f16, 100 MB
#define OFF_WQ   402653184UL
#define OFF_WK   403832832UL
#define OFF_WV   405012480UL
#define OFF_WO   406192128UL
#define OFF_PH   407371776UL   // probs f16 [h][i][j], 1.5 MB

__global__ __launch_bounds__(256) void cast_f32_f16(const float* __restrict__ in,
                                                    f16* __restrict__ out, int n8) {
    int i = blockIdx.x * 256 + threadIdx.x;
    if (i >= n8) return;
    const float4* p = (const float4*)in;
    float4 a = p[2*i], b = p[2*i+1];
    f16x8 o;
    o[0]=(f16)a.x; o[1]=(f16)a.y; o[2]=(f16)a.z; o[3]=(f16)a.w;
    o[4]=(f16)b.x; o[5]=(f16)b.y; o[6]=(f16)b.z; o[7]=(f16)b.w;
    ((f16x8*)out)[i] = o;
}

enum { MODE_QK = 0, MODE_V = 1, MODE_SPLIT = 2, MODE_CTX = 3, MODE_OUT = 4 };

__device__ __forceinline__ void gl_lds16(const f16* g, f16* l) {
    auto gp = (const __attribute__((address_space(1))) f16*)(g);
    auto lp = (__attribute__((address_space(3))) f16*)(l);
    __builtin_amdgcn_global_load_lds(gp, lp, 16, 0, 0);
}

__device__ __forceinline__ f16x8 ds_read_b128_f16(unsigned off) {
    f16x8 r;
    asm volatile("ds_read_b128 %0, %1" : "=v"(r) : "v"(off));
    return r;
}

// ---------------------------------------------------------------------------
// OLD m97-pattern NT GEMM (kept ONLY for MODE_SPLIT scores: small 128x128
// tiles give 768 blocks -> full-machine coverage for the split-K phase).
// Known-good from round 0.
// ---------------------------------------------------------------------------
template<int MODE>
__global__ __launch_bounds__(256) void gemm_fast(
    const f16* __restrict__ A, const f16* __restrict__ B,
    float* __restrict__ outF, f16* __restrict__ outH,
    const float* __restrict__ bias, float scale,
    int lda, int ldb, int K)
{
    __shared__ f16 As[128*64];
    __shared__ f16 Bs[128*64];
    const int tid = threadIdx.x;
    const int wv = tid >> 6, ln = tid & 63;
    const int lrow = ln & 15, quad = ln >> 4;
    const int wm = wv >> 1, wn = wv & 1;
    const int m0 = blockIdx.y * 128;
    const int n0 = blockIdx.x * 128;
    const int z = blockIdx.z;
    int h = 0, sp = 0;
    if constexpr (MODE == MODE_SPLIT) {
        h = z >> 4; sp = z & 15;
        A += (long)h*4194304 + sp*1024;
        B += (long)h*4194304 + sp*1024;
    } else if constexpr (MODE == MODE_CTX) {
        A += (long)z * 65536;
        B += (long)z * 4194304;
    }

    const int srow = wv*32 + (ln >> 3);
    const int scol = ((ln & 7) ^ (srow & 7)) << 3;
    const f16* ga = A + (long)(m0 + srow)*lda + scol;
    const f16* gb = B + (long)(n0 + srow)*ldb + scol;

    f32x4 acc[4][4] = {};

    for (int k0 = 0; k0 < K; k0 += 64) {
        __syncthreads();
        #pragma unroll
        for (int t = 0; t < 4; t++) {
            gl_lds16(ga + (long)t*8*lda, As + (wv*4 + t)*512);
            gl_lds16(gb + (long)t*8*ldb, Bs + (wv*4 + t)*512);
        }
        ga += 64; gb += 64;
        __syncthreads();
        #pragma unroll
        for (int ks = 0; ks < 2; ks++) {
            const int slot = ((ks*4 + quad) ^ (lrow & 7)) << 3;
            f16x8 af[4], bf[4];
            #pragma unroll
            for (int i = 0; i < 4; i++)
                af[i] = *(const f16x8*)&As[(wm*64 + i*16 + lrow)*64 + slot];
            #pragma unroll
            for (int j = 0; j < 4; j++)
                bf[j] = *(const f16x8*)&Bs[(wn*64 + j*16 + lrow)*64 + slot];
            #pragma unroll
            for (int i = 0; i < 4; i++)
                #pragma unroll
                for (int j = 0; j < 4; j++)
                    acc[i][j] = __builtin_amdgcn_mfma_f32_16x16x32_f16(af[i], bf[j], acc[i][j], 0, 0, 0);
        }
    }

    #pragma unroll
    for (int i = 0; i < 4; i++) {
        #pragma unroll
        for (int j = 0; j < 4; j++) {
            #pragma unroll
            for (int r = 0; r < 4; r++) {
                int m = m0 + wm*64 + i*16 + quad*4 + r;
                int n = n0 + wn*64 + j*16 + lrow;
                float v = acc[i][j][r];
                if constexpr (MODE == MODE_QK) {
                    v = (v + bias[n]) * scale;
                    outH[(((long)((n>>6)*256 + (m&255))*256 + (m>>8))<<6) + (n&63)] = (f16)v;
                } else if constexpr (MODE == MODE_V) {
                    v = v + bias[n];
                    outH[(((long)((n>>6)*256 + (m>>8))*64 + (n&63))<<8) + (m&255)] = (f16)v;
                } else if constexpr (MODE == MODE_SPLIT) {
                    outF[(long)sp*786432 + h*65536 + m*256 + n] = v;
                } else if constexpr (MODE == MODE_CTX) {
                    outH[((long)((n>>6)*256 + m))*768 + z*64 + (n&63)] = (f16)v;
                } else {
                    outF[(long)m*768 + n] = v + bias[n];
                }
            }
        }
    }
}

// ---------------------------------------------------------------------------
// NEW: 256x128-tile, BK=64, 8 waves (4M x 2N, wave tile 64x64), TRIPLE-
// buffered LDS (3 x 48 KB = 144 KB). During tile t (compute reads buf t%3)
// we stage tile t+2 into buf (t+2)%3; tile t+1 lands in the third buffer.
// => no LDS region is ever written while readable (the round-1 race is
// structurally impossible). One counted vmcnt(6) per tile boundary (6 =
// tile t+2's in-flight issues); vmcnt(0) only at the final boundary.
// 2 phases/tile (k-half quadrants, 16 MFMA each), template phase body:
// ds_read frags | stage 3 issues | barrier | lgkmcnt(0)+sched_barrier |
// setprio(1) MFMA setprio(0) | [boundary: vmcnt] | barrier.
// Bank conflicts: XOR-segment swizzle on the global SOURCE column (linear
// LDS dest, rule #21), un-swizzled at ds_read -> 2-way max (free, =round 0).
// ---------------------------------------------------------------------------
template<int MODE>
__global__ __launch_bounds__(512, 2) void gemm3b(
    const f16* __restrict__ A, const f16* __restrict__ B,
    float* __restrict__ outF, f16* __restrict__ outH,
    const float* __restrict__ bias, float scale,
    int lda, int ldb, int K)
{
    __shared__ f16 As[3][16384];   // [buf][256 rows][64]  32 KB each
    __shared__ f16 Bs[3][8192];    // [buf][128 rows][64]  16 KB each
    const int tid = threadIdx.x;
    const int wv = tid >> 6, ln = tid & 63;
    const int lrow = ln & 15, quad = ln >> 4;
    const int wm = wv >> 1, wn = wv & 1;   // 4M x 2N wave grid; wave tile 64x64

    int bx, by, z = 0;
    if constexpr (MODE == MODE_CTX) {
        bx = blockIdx.x; by = 0; z = blockIdx.z;
    } else {
        // bijective XCD swizzle: 1536 = 8 * 192. Each XCD gets a contiguous
        // band of m-tiles; consecutive blocks within an XCD share the A panel.
        int lin = blockIdx.x;
        int swz = (lin & 7) * 192 + (lin >> 3);
        bx = swz % 6; by = swz / 6;
    }
    const int m0 = by * 256, n0 = bx * 128;

    const f16* Ab = A; const f16* Bb = B;
    if constexpr (MODE == MODE_CTX) { Ab += (long)z*65536; Bb += (long)z*4194304; }

    // staging geometry: 512 thr x 16 B = 8 KB/issue = 64 rows x 128 B.
    // A tile = 4 issues, B tile = 2 issues -> 6 issues (VMEM ops/wave) per tile.
    const int srow = tid >> 3;                              // 0..63
    const int scol = (((tid & 7) ^ (srow & 7)) << 3);       // pre-swizzled source col
    const f16* gA = Ab + (long)(m0 + srow)*lda + scol;
    const f16* gB = Bb + (long)(n0 + srow)*ldb + scol;

    typedef __attribute__((address_space(3))) f16 lds_f16;
    const unsigned asBase = (unsigned)(uintptr_t)(lds_f16*)&As[0][0];
    const unsigned bsBase = (unsigned)(uintptr_t)(lds_f16*)&Bs[0][0];

    const int NT = K >> 6;   // >= 4 for all modes

    auto stageA = [&](int buf, int kOff, int iss) {
        gl_lds16(gA + (long)iss*64*lda + kOff, &As[buf][iss*4096 + wv*512]);
    };
    auto stageB = [&](int buf, int kOff, int iss) {
        gl_lds16(gB + (long)iss*64*ldb + kOff, &Bs[buf][iss*4096 + wv*512]);
    };

    // prologue: stage tiles 0 and 1 fully (12 issues); wait tile 0 (6 newest
    // outstanding allowed = tile 1's issues).
    #pragma unroll
    for (int tt = 0; tt < 2; ++tt) {
        stageA(tt, tt*64, 0); stageA(tt, tt*64, 1);
        stageA(tt, tt*64, 2); stageA(tt, tt*64, 3);
        stageB(tt, tt*64, 0); stageB(tt, tt*64, 1);
    }
    asm volatile("s_waitcnt vmcnt(6)" ::: "memory");
    __builtin_amdgcn_sched_barrier(0);
    __builtin_amdgcn_s_barrier();

    f32x4 acc[4][4] = {};
    int buf = 0;
    for (int t = 0; t < NT; ++t) {
        const int sb = (buf >= 1) ? buf - 1 : buf + 2;      // (t+2)%3
        const bool doStage = (t + 2) < NT;
        const int kOff = (t + 2) << 6;
        const unsigned aB = asBase + (unsigned)buf * 32768u;
        const unsigned bB = bsBase + (unsigned)buf * 16384u;
        #pragma unroll
        for (int ph = 0; ph < 2; ++ph) {
            const unsigned slotB = (unsigned)(((ph*4 + quad) ^ (lrow & 7)) << 4);
            f16x8 af[4], bf[4];
            #pragma unroll
            for (int i = 0; i < 4; ++i)
                af[i] = ds_read_b128_f16(aB + ((unsigned)(wm*64 + i*16 + lrow) << 7) + slotB);
            #pragma unroll
            for (int j = 0; j < 4; ++j)
                bf[j] = ds_read_b128_f16(bB + ((unsigned)(wn*64 + j*16 + lrow) << 7) + slotB);
            if (doStage) {
                if (ph == 0) { stageA(sb, kOff, 0); stageA(sb, kOff, 1); stageB(sb, kOff, 0); }
                else         { stageA(sb, kOff, 2); stageA(sb, kOff, 3); stageB(sb, kOff, 1); }
            }
            __builtin_amdgcn_s_barrier();
            asm volatile("s_waitcnt lgkmcnt(0)" ::: "memory");
            __builtin_amdgcn_sched_barrier(0);              // rule #18: pin MFMA after wait
            __builtin_amdgcn_s_setprio(1);
            #pragma unroll
            for (int i = 0; i < 4; ++i)
                #pragma unroll
                for (int j = 0; j < 4; ++j)
                    acc[i][j] = __builtin_amdgcn_mfma_f32_16x16x32_f16(af[i], bf[j], acc[i][j], 0, 0, 0);
            __builtin_amdgcn_s_setprio(0);
            if (ph == 1 && t < NT - 1) {
                // boundary: tile t+1 must be fully landed; the only newer
                // issues are tile t+2's 6 (if staged this tile).
                if (t <= NT - 3) asm volatile("s_waitcnt vmcnt(6)" ::: "memory");
                else             asm volatile("s_waitcnt vmcnt(0)" ::: "memory");
                __builtin_amdgcn_sched_barrier(0);
            }
            __builtin_amdgcn_s_barrier();
        }
        buf = (buf == 2) ? 0 : buf + 1;
    }

    // Epilogue. D-layout: col(n) = lane&15, row(m) = quad*4 + reg.
    #pragma unroll
    for (int i = 0; i < 4; ++i) {
        #pragma unroll
        for (int j = 0; j < 4; ++j) {
            #pragma unroll
            for (int r = 0; r < 4; ++r) {
                int m = m0 + wm*64 + i*16 + quad*4 + r;
                int n = n0 + wn*64 + j*16 + lrow;
                float v = acc[i][j][r];
                if constexpr (MODE == MODE_QK) {
                    v = (v + bias[n]) * scale;
                    outH[(((long)((n>>6)*256 + (m&255))*256 + (m>>8))<<6) + (n&63)] = (f16)v;
                } else if constexpr (MODE == MODE_V) {
                    v = v + bias[n];
                    outH[(((long)((n>>6)*256 + (m>>8))*64 + (n&63))<<8) + (m&255)] = (f16)v;
                } else if constexpr (MODE == MODE_CTX) {
                    outH[((long)((n>>6)*256 + m))*768 + z*64 + (n&63)] = (f16)v;
                } else { // MODE_OUT
                    outF[(long)m*768 + n] = v + bias[n];
                }
            }
        }
    }
}

// Fused 16-way split-K reduce + shared softmax over j. One block per (h,i) row.
__global__ __launch_bounds__(256) void softmax_k(const float* __restrict__ Sp,
                                                 float* __restrict__ pOut,
                                                 f16* __restrict__ Ph) {
    __shared__ float red[8];
    const int row = blockIdx.x;   // h*256 + i
    const int t = threadIdx.x;    // j
    float v = 0.f;
    #pragma unroll
    for (int s = 0; s < 16; s++)
        v += Sp[(long)s*786432 + (long)row*256 + t];
    float mx = v;
    #pragma unroll
    for (int o = 32; o; o >>= 1) mx = fmaxf(mx, __shfl_xor(mx, o, 64));
    if ((t & 63) == 0) red[t >> 6] = mx;
    __syncthreads();
    mx = fmaxf(fmaxf(red[0], red[1]), fmaxf(red[2], red[3]));
    float e = expf(v - mx);
    float s = e;
    #pragma unroll
    for (int o = 32; o; o >>= 1) s += __shfl_xor(s, o, 64);
    if ((t & 63) == 0) red[4 + (t >> 6)] = s;
    __syncthreads();
    s = red[4] + red[5] + red[6] + red[7];
    float p = e / s;
    pOut[(long)row*256 + t] = p;
    Ph[(long)row*256 + t] = (f16)p;
}

extern "C" void kernel_launch(void* const* d_in, const int* in_sizes, int n_in,
                              void* d_out, int out_size, void* d_ws, size_t ws_size,
                              hipStream_t stream) {
    const float* x  = (const float*)d_in[0];
    const float* Wq = (const float*)d_in[1];
    const float* bq = (const float*)d_in[2];
    const float* Wk = (const float*)d_in[3];
    const float* bk = (const float*)d_in[4];
    const float* Wv = (const float*)d_in[5];
    const float* bv = (const float*)d_in[6];
    const float* Wo = (const float*)d_in[7];
    const float* bo = (const float*)d_in[8];
    float* out   = (float*)d_out;
    float* probs = out + 50331648L;

    char* ws = (char*)d_ws;
    f16*   Xh   = (f16*)(ws + OFF_XH);
    float* Sp   = (float*)(ws + OFF_XH);  // alias: Xh dead after V-proj
    f16*   CTXh = (f16*)(ws + OFF_XH);    // alias: Sp dead after softmax
    f16*   Qt   = (f16*)(ws + OFF_QT);
    f16*   Kt   = (f16*)(ws + OFF_KT);
    f16*   Vt   = (f16*)(ws + OFF_VT);
    f16*   Wqh  = (f16*)(ws + OFF_WQ);
    f16*   Wkh  = (f16*)(ws + OFF_WK);
    f16*   Wvh  = (f16*)(ws + OFF_WV);
    f16*   Woh  = (f16*)(ws + OFF_WO);
    f16*   Ph   = (f16*)(ws + OFF_PH);

    cast_f32_f16<<<24576, 256, 0, stream>>>(x,  Xh,  6291456);
    cast_f32_f16<<<288,   256, 0, stream>>>(Wq, Wqh, 73728);
    cast_f32_f16<<<288,   256, 0, stream>>>(Wk, Wkh, 73728);
    cast_f32_f16<<<288,   256, 0, stream>>>(Wv, Wvh, 73728);
    cast_f32_f16<<<288,   256, 0, stream>>>(Wo, Woh, 73728);

    // projections: M=65536, N=768, K=768 -> 256 m-tiles x 6 n-tiles (256x128)
    gemm3b<MODE_QK><<<1536, 512, 0, stream>>>(Xh, Wqh, nullptr, Qt, bq, 1.0f/128.0f, 768, 768, 768);
    gemm3b<MODE_QK><<<1536, 512, 0, stream>>>(Xh, Wkh, nullptr, Kt, bk, 1.0f,        768, 768, 768);
    gemm3b<MODE_V ><<<1536, 512, 0, stream>>>(Xh, Wvh, nullptr, Vt, bv, 1.0f,        768, 768, 768);

    // scores: per head M=N=256, K=16384 -> 16-way split-K, fp32 partials in Sp
    gemm_fast<MODE_SPLIT><<<dim3(2, 2, 192), 256, 0, stream>>>(Qt, Kt, Sp, nullptr, nullptr, 1.0f, 16384, 16384, 1024);

    // fused reduce + softmax (3072 rows)
    softmax_k<<<3072, 256, 0, stream>>>(Sp, probs, Ph);

    // context: per head M=256(i), N=16384(r,d) -> 128 n-tiles x 12 heads, K=256
    gemm3b<MODE_CTX><<<dim3(128, 1, 12), 512, 0, stream>>>(Ph, Vt, nullptr, CTXh, nullptr, 1.0f, 256, 256, 256);

    // output projection: M=65536, N=768, K=768, fp32 out + bias
    gemm3b<MODE_OUT><<<1536, 512, 0, stream>>>(CTXh, Woh, out, nullptr, bo, 1.0f, 768, 768, 768);
}